// Round 13
// baseline (730.684 us; speedup 1.0000x reference)
//
#include <hip/hip_runtime.h>
#include <math.h>

typedef __bf16 bf16;
typedef __attribute__((ext_vector_type(4))) __bf16 bf16x4;
typedef __attribute__((ext_vector_type(8))) __bf16 bf16x8;
typedef __attribute__((ext_vector_type(4))) float f32x4;

#define T_STEPS 128
#define B_SZ    256
#define V_SZ    256
#define N_SZ    1024
#define NROWS   (T_STEPS * B_SZ)   // 32768
#define RST     36                 // step reduction stride (floats, 32+4)
#define LST     17                 // loss reduction stride (floats)
#define NGRP    16                 // row groups (16 batch rows each)
#define NCB2    32                 // blocks (arrivals) per group

__device__ __forceinline__ float fast_tanh(float x) {
    float e = __expf(2.0f * x);
    return 1.0f - 2.0f / (e + 1.0f);   // exact at +-inf, no NaN
}

// ---------------- fp32 -> bf16 contiguous convert ----------------
__global__ void k_convert(const float* __restrict__ src, bf16* __restrict__ dst, int n) {
    int i = (blockIdx.x * blockDim.x + threadIdx.x) * 4;
    if (i < n) {
        float4 v = *(const float4*)(src + i);
        bf16x4 o;
        o.x = (bf16)v.x; o.y = (bf16)v.y; o.z = (bf16)v.z; o.w = (bf16)v.w;
        *(bf16x4*)(dst + i) = o;
    }
}

// ---------------- fp32 (R x C) -> bf16 transpose (C x R) ----------------
__global__ void k_transpose_cvt(const float* __restrict__ src, bf16* __restrict__ dst,
                                int R, int C) {
    __shared__ float tile[32][33];
    int c0 = blockIdx.x * 32;
    int r0 = blockIdx.y * 32;
    int tx = threadIdx.x & 31;
    int ty = threadIdx.x >> 5;   // 0..7
#pragma unroll
    for (int i = 0; i < 32; i += 8)
        tile[ty + i][tx] = src[(size_t)(r0 + ty + i) * C + c0 + tx];
    __syncthreads();
#pragma unroll
    for (int i = 0; i < 32; i += 8)
        dst[(size_t)(c0 + ty + i) * R + r0 + tx] = (bf16)tile[tx][ty + i];
}

// ---------------- persistent recurrence, TWO groups per block -----------------------
// 256 blocks x 512 threads. gp=bid>>5 (0..7) -> groups g0=2gp, g1=2gp+1 (16 rows each,
// 32 blocks per group). c=bid&31 -> cols [c*32,+32). The sync round-trip delta is paid
// once per ROUND (two group-steps): A-loads for both groups issued together, epilogues
// run in parallel on thread halves, tid0 arrives+polls while loss epilogue runs.
// Loss GEMM: vocab slice s=c>>1, K-half h=c&1 (waves w>>2==h), bf16 partial logits
// in 2 buffers summed by k_lred. No acquire fences => weights stay L2-hot.
__global__ __launch_bounds__(512, 2) void k_rnn(
    const bf16* __restrict__ Xb,    // 32768 x 256 (bf16 inputs, t-major)
    const bf16* __restrict__ Wxt,   // 1024 x 256  = Wx^T
    const bf16* __restrict__ Wht,   // 1024 x 1024 = Wh^T
    const bf16* __restrict__ Wot,   // 256 x 1024  = Wo^T
    const float* __restrict__ bias,
    bf16* __restrict__ XH,          // 32768 x 1024 H states
    unsigned int* __restrict__ Lgu, // bf16-pair partial logits [h][p][s][256 rows][8]
    int* __restrict__ cnt)          // [NGRP * T_STEPS], zeroed
{
    __shared__ float red0[8 * 16 * RST];   // 18.4 KB g0 step K-reduce
    __shared__ float red1[8 * 16 * RST];   // 18.4 KB g1
    __shared__ float lred0[4 * 16 * LST];  // 4.4 KB  g0 loss K-reduce
    __shared__ float lred1[4 * 16 * LST];  // 4.4 KB  g1
    const int tid  = threadIdx.x;
    const int lane = tid & 63;
    const int w    = tid >> 6;        // 0..7
    const int quad = lane >> 4;
    const int l15  = lane & 15;
    const int gp = blockIdx.x >> 5;   // group pair 0..7
    const int c  = blockIdx.x & 31;   // col block 0..31
    const int g0 = gp * 2, g1 = gp * 2 + 1;
    const int m00 = g0 * 16, m01 = g1 * 16;
    const int n0 = c * 32;
    const int k0 = w * 128;           // K-slice for Wh / Wot
    const int v0 = w * 32;            // K-slice for Xproj (V=256/8)
    const int h  = c & 1;             // loss K-half
    const int s  = c >> 1;            // vocab slice 0..15
    const bool lossw = ((w >> 2) == h);
    const int wl = w & 3;
    int* gc0 = cnt + g0 * T_STEPS;
    int* gc1 = cnt + g1 * T_STEPS;

    // B fragments (shared by both groups — same cols)
    const bf16* Bp = Wht + (size_t)(n0 + l15) * N_SZ + k0 + quad * 8;
    bf16x8 b[2][4];
#pragma unroll
    for (int nt = 0; nt < 2; ++nt)
#pragma unroll
        for (int kc = 0; kc < 4; ++kc)
            b[nt][kc] = *(const bf16x8*)&Bp[(size_t)(nt * 16) * N_SZ + kc * 32];
    bf16x8 bx[2];
#pragma unroll
    for (int nt = 0; nt < 2; ++nt)
        bx[nt] = *(const bf16x8*)&Wxt[(size_t)(n0 + nt * 16 + l15) * V_SZ + v0 + quad * 8];
    bf16x8 bo[4];
    if (lossw) {
#pragma unroll
        for (int kc = 0; kc < 4; ++kc)
            bo[kc] = *(const bf16x8*)&Wot[(size_t)(s * 16 + l15) * N_SZ + k0 + kc * 32 + quad * 8];
    }

    // publish mapping: tid<256 -> g0, tid>=256 -> g1; each thread one dword (2 cols)
    const int  et   = tid & 255;
    const int  orow = et >> 4;           // 0..15
    const int  ocol = (et & 15) * 2;     // 0..30
    const int  mg   = (tid >= 256) ? m01 : m00;
    float* redp = (tid >= 256) ? red1 : red0;
    const float bias0 = bias[n0 + ocol];
    const float bias1 = bias[n0 + ocol + 1];
    // loss epilogue mapping: tid 128..255 -> g0, 384..511 -> g1 (tid0's wave free to poll)
    const bool lactive = (tid >= 128 && tid < 256) || (tid >= 384);
    const int  lt   = (tid >= 384) ? (tid - 384) : (tid - 128);
    const int  lrow = lt >> 3, lvp = lt & 7;
    float* lredp = (tid >= 384) ? lred1 : lred0;
    const int  lm  = (tid >= 384) ? m01 : m00;
    unsigned int* XHu = (unsigned int*)XH;
    const f32x4 zz = {0.f, 0.f, 0.f, 0.f};

    // ---------------- t = 0 round: H_0 = tanh(Xproj_0 + bias), both groups ----------
    {
        bf16x8 ax0 = *(const bf16x8*)&Xb[(size_t)(m00 + l15) * V_SZ + v0 + quad * 8];
        bf16x8 ax1 = *(const bf16x8*)&Xb[(size_t)(m01 + l15) * V_SZ + v0 + quad * 8];
        f32x4 acc0[2] = {zz, zz}, acc1[2] = {zz, zz};
#pragma unroll
        for (int nt = 0; nt < 2; ++nt) {
            acc0[nt] = __builtin_amdgcn_mfma_f32_16x16x32_bf16(ax0, bx[nt], acc0[nt], 0, 0, 0);
            acc1[nt] = __builtin_amdgcn_mfma_f32_16x16x32_bf16(ax1, bx[nt], acc1[nt], 0, 0, 0);
        }
#pragma unroll
        for (int nt = 0; nt < 2; ++nt)
#pragma unroll
            for (int r = 0; r < 4; ++r) {
                red0[(w * 16 + quad * 4 + r) * RST + nt * 16 + l15] = acc0[nt][r];
                red1[(w * 16 + quad * 4 + r) * RST + nt * 16 + l15] = acc1[nt][r];
            }
        __syncthreads();
        float s0 = bias0, s1 = bias1;
#pragma unroll
        for (int w2 = 0; w2 < 8; ++w2) {
            float2 v = *(const float2*)&redp[(w2 * 16 + orow) * RST + ocol];
            s0 += v.x; s1 += v.y;
        }
        bf16 r0 = (bf16)fast_tanh(s0);
        bf16 r1 = (bf16)fast_tanh(s1);
        unsigned int outw = (unsigned int)__builtin_bit_cast(unsigned short, r0)
                          | ((unsigned int)__builtin_bit_cast(unsigned short, r1) << 16);
        size_t oidx = (((size_t)mg + orow) * N_SZ + n0 + ocol) >> 1;
        __hip_atomic_store(&XHu[oidx], outw, __ATOMIC_RELAXED, __HIP_MEMORY_SCOPE_AGENT);
        asm volatile("s_waitcnt vmcnt(0)" ::: "memory");
        __syncthreads();
        if (tid == 0) {
            __hip_atomic_fetch_add(&gc0[0], 1, __ATOMIC_RELAXED, __HIP_MEMORY_SCOPE_AGENT);
            __hip_atomic_fetch_add(&gc1[0], 1, __ATOMIC_RELAXED, __HIP_MEMORY_SCOPE_AGENT);
            while (__hip_atomic_load(&gc0[0], __ATOMIC_RELAXED, __HIP_MEMORY_SCOPE_AGENT) < NCB2)
                __builtin_amdgcn_s_sleep(1);
            while (__hip_atomic_load(&gc1[0], __ATOMIC_RELAXED, __HIP_MEMORY_SCOPE_AGENT) < NCB2)
                __builtin_amdgcn_s_sleep(1);
        }
        __syncthreads();
    }

    // ---------------- rounds t = 1..127 (step+loss) and t = 128 (loss tail) ---------
    for (int t = 1; t <= T_STEPS; ++t) {
        const bool do_step = (t < T_STEPS);

        // Xb prefetch for step t
        bf16x8 ax0, ax1;
        if (do_step) {
            ax0 = *(const bf16x8*)&Xb[((size_t)t * B_SZ + m00 + l15) * V_SZ + v0 + quad * 8];
            ax1 = *(const bf16x8*)&Xb[((size_t)t * B_SZ + m01 + l15) * V_SZ + v0 + quad * 8];
        }

        // A fragments for both groups, plane t-1 (poll for cnt[t-1] done last round)
        const bf16* Ap0 = XH + ((size_t)(t - 1) * B_SZ + m00 + l15) * N_SZ + k0 + quad * 8;
        const bf16* Ap1 = XH + ((size_t)(t - 1) * B_SZ + m01 + l15) * N_SZ + k0 + quad * 8;
        bf16x8 a0[4], a1[4];
#pragma unroll
        for (int kc = 0; kc < 4; ++kc) {
            a0[kc] = *(const bf16x8*)&Ap0[kc * 32];
            a1[kc] = *(const bf16x8*)&Ap1[kc * 32];
        }

        if (do_step) {
            f32x4 acc0[2] = {zz, zz}, acc1[2] = {zz, zz};
#pragma unroll
            for (int nt = 0; nt < 2; ++nt) {
                acc0[nt] = __builtin_amdgcn_mfma_f32_16x16x32_bf16(ax0, bx[nt], acc0[nt], 0, 0, 0);
                acc1[nt] = __builtin_amdgcn_mfma_f32_16x16x32_bf16(ax1, bx[nt], acc1[nt], 0, 0, 0);
            }
#pragma unroll
            for (int kc = 0; kc < 4; ++kc)
#pragma unroll
                for (int nt = 0; nt < 2; ++nt) {
                    acc0[nt] = __builtin_amdgcn_mfma_f32_16x16x32_bf16(a0[kc], b[nt][kc], acc0[nt], 0, 0, 0);
                    acc1[nt] = __builtin_amdgcn_mfma_f32_16x16x32_bf16(a1[kc], b[nt][kc], acc1[nt], 0, 0, 0);
                }
#pragma unroll
            for (int nt = 0; nt < 2; ++nt)
#pragma unroll
                for (int r = 0; r < 4; ++r) {
                    red0[(w * 16 + quad * 4 + r) * RST + nt * 16 + l15] = acc0[nt][r];
                    red1[(w * 16 + quad * 4 + r) * RST + nt * 16 + l15] = acc1[nt][r];
                }
        }
        if (lossw) {
            f32x4 lacc0 = zz, lacc1 = zz;
#pragma unroll
            for (int kc = 0; kc < 4; ++kc) {
                lacc0 = __builtin_amdgcn_mfma_f32_16x16x32_bf16(a0[kc], bo[kc], lacc0, 0, 0, 0);
                lacc1 = __builtin_amdgcn_mfma_f32_16x16x32_bf16(a1[kc], bo[kc], lacc1, 0, 0, 0);
            }
#pragma unroll
            for (int r = 0; r < 4; ++r) {
                lred0[(wl * 16 + quad * 4 + r) * LST + l15] = lacc0[r];
                lred1[(wl * 16 + quad * 4 + r) * LST + l15] = lacc1[r];
            }
        }
        __syncthreads();

        // parallel step epilogues on thread halves
        if (do_step) {
            float s0 = bias0, s1 = bias1;
#pragma unroll
            for (int w2 = 0; w2 < 8; ++w2) {
                float2 v = *(const float2*)&redp[(w2 * 16 + orow) * RST + ocol];
                s0 += v.x; s1 += v.y;
            }
            bf16 r0 = (bf16)fast_tanh(s0);
            bf16 r1 = (bf16)fast_tanh(s1);
            unsigned int outw = (unsigned int)__builtin_bit_cast(unsigned short, r0)
                              | ((unsigned int)__builtin_bit_cast(unsigned short, r1) << 16);
            size_t oidx = (((size_t)t * B_SZ + mg + orow) * N_SZ + n0 + ocol) >> 1;
            __hip_atomic_store(&XHu[oidx], outw, __ATOMIC_RELAXED, __HIP_MEMORY_SCOPE_AGENT);
            asm volatile("s_waitcnt vmcnt(0)" ::: "memory");
        }
        __syncthreads();

        // tid0: arrive both groups + poll next round (overlaps loss epilogue below)
        if (tid == 0 && do_step) {
            __hip_atomic_fetch_add(&gc0[t], 1, __ATOMIC_RELAXED, __HIP_MEMORY_SCOPE_AGENT);
            __hip_atomic_fetch_add(&gc1[t], 1, __ATOMIC_RELAXED, __HIP_MEMORY_SCOPE_AGENT);
            while (__hip_atomic_load(&gc0[t], __ATOMIC_RELAXED, __HIP_MEMORY_SCOPE_AGENT) < NCB2)
                __builtin_amdgcn_s_sleep(1);
            while (__hip_atomic_load(&gc1[t], __ATOMIC_RELAXED, __HIP_MEMORY_SCOPE_AGENT) < NCB2)
                __builtin_amdgcn_s_sleep(1);
        }
        // loss epilogue for plane t-1 (parallel thread ranges)
        if (lactive) {
            float sa = 0.f, sb = 0.f;
#pragma unroll
            for (int w2 = 0; w2 < 4; ++w2) {
                sa += lredp[(w2 * 16 + lrow) * LST + lvp * 2];
                sb += lredp[(w2 * 16 + lrow) * LST + lvp * 2 + 1];
            }
            bf16 pa = (bf16)sa, pb = (bf16)sb;
            unsigned int pw = (unsigned int)__builtin_bit_cast(unsigned short, pa)
                            | ((unsigned int)__builtin_bit_cast(unsigned short, pb) << 16);
            Lgu[((((size_t)h * T_STEPS + (t - 1)) * 16 + s) * B_SZ + lm + lrow) * 8 + lvp] = pw;
        }
        __syncthreads();   // protects red/lred reuse next round; releases poll
    }
}

// ---------------- final: sum 2 partial-logit halves, log-softmax, loss --------------
// 256 blocks x 256 threads (4 waves); block 128 rows, wave 32 rows.
// Partial logits: bf16 [h][plane][slice 16][row-in-plane 256][16 vocab].
__global__ __launch_bounds__(256) void k_lred(
    const bf16* __restrict__ Lg,
    const float* __restrict__ labels,
    const float* __restrict__ ob,
    float* __restrict__ out)
{
    __shared__ float bt[4];
    const size_t HS = (size_t)NROWS * V_SZ;   // half stride in bf16 elems
    const int tid  = threadIdx.x;
    const int lane = tid & 63;
    const int w    = tid >> 6;       // 0..3
    const int cs   = lane >> 2;      // vocab slab 0..15
    const int vi   = (lane & 3) * 4; // offset in slab
    const float4 ob4 = *(const float4*)&ob[cs * 16 + vi];

    float wtot = 0.f;
    for (int i = 0; i < 32; ++i) {
        int row  = blockIdx.x * 128 + w * 32 + i;
        int p    = row >> 8;
        int brow = row & 255;
        size_t idx = (((size_t)p * 16 + cs) * B_SZ + brow) * 16 + vi;
        bf16x4 va = *(const bf16x4*)&Lg[idx];
        bf16x4 vb = *(const bf16x4*)&Lg[HS + idx];
        float l0 = (float)va.x + (float)vb.x + ob4.x;
        float l1 = (float)va.y + (float)vb.y + ob4.y;
        float l2 = (float)va.z + (float)vb.z + ob4.z;
        float l3 = (float)va.w + (float)vb.w + ob4.w;
        float mx = fmaxf(fmaxf(l0, l1), fmaxf(l2, l3));
#pragma unroll
        for (int sft = 1; sft < 64; sft <<= 1)
            mx = fmaxf(mx, __shfl_xor(mx, sft, 64));
        float sume = __expf(l0 - mx) + __expf(l1 - mx) + __expf(l2 - mx) + __expf(l3 - mx);
        const float4 lb = *(const float4*)&labels[(size_t)row * V_SZ + cs * 16 + vi];
        float labs = lb.x + lb.y + lb.z + lb.w;
        float labv = lb.x * l0 + lb.y * l1 + lb.z * l2 + lb.w * l3;
#pragma unroll
        for (int sft = 1; sft < 64; sft <<= 1) {
            sume += __shfl_xor(sume, sft, 64);
            labs += __shfl_xor(labs, sft, 64);
            labv += __shfl_xor(labv, sft, 64);
        }
        float lse = mx + __logf(sume);
        wtot += labs * lse - labv;
    }
    if (lane == 0) bt[w] = wtot;
    __syncthreads();
    if (tid == 0)
        atomicAdd(out, (bt[0] + bt[1] + bt[2] + bt[3]) * (1.0f / (float)NROWS));
}

extern "C" void kernel_launch(void* const* d_in, const int* in_sizes, int n_in,
                              void* d_out, int out_size, void* d_ws, size_t ws_size,
                              hipStream_t stream)
{
    const float* inputs  = (const float*)d_in[0];
    const float* labels  = (const float*)d_in[1];
    const float* weights = (const float*)d_in[2];
    const float* bias    = (const float*)d_in[3];
    const float* out_w   = (const float*)d_in[4];
    const float* out_b   = (const float*)d_in[5];
    float* out = (float*)d_out;

    char* ws = (char*)d_ws;
    bf16* XH  = (bf16*)ws;  ws += (size_t)NROWS * N_SZ * 2;       // 64 MB H states
    bf16* Xb  = (bf16*)ws;  ws += (size_t)NROWS * V_SZ * 2;       // 16 MB
    bf16* Lg  = (bf16*)ws;  ws += (size_t)2 * NROWS * V_SZ * 2;   // 32 MB partial logits
    bf16* Wxt = (bf16*)ws;  ws += (size_t)N_SZ * V_SZ * 2;        // 0.5 MB (Wx^T)
    bf16* Wht = (bf16*)ws;  ws += (size_t)N_SZ * N_SZ * 2;        // 2 MB   (Wh^T)
    bf16* Wot = (bf16*)ws;  ws += (size_t)V_SZ * N_SZ * 2;        // 0.5 MB (Wo^T)
    int*  cnt = (int*)ws;   ws += (size_t)NGRP * T_STEPS * 4;     // 8 KB sync counters

    hipMemsetAsync(out, 0, sizeof(float), stream);
    hipMemsetAsync(cnt, 0, (size_t)NGRP * T_STEPS * 4, stream);

    k_convert<<<dim3(NROWS * V_SZ / 1024), 256, 0, stream>>>(inputs, Xb, NROWS * V_SZ);
    k_transpose_cvt<<<dim3(N_SZ / 32, V_SZ / 32), 256, 0, stream>>>(weights, Wxt, V_SZ, N_SZ);
    k_transpose_cvt<<<dim3(N_SZ / 32, N_SZ / 32), 256, 0, stream>>>(
        weights + (size_t)V_SZ * N_SZ, Wht, N_SZ, N_SZ);
    k_transpose_cvt<<<dim3(V_SZ / 32, N_SZ / 32), 256, 0, stream>>>(out_w, Wot, N_SZ, V_SZ);

    k_rnn<<<dim3(256), 512, 0, stream>>>(Xb, Wxt, Wht, Wot, bias, XH,
                                         (unsigned int*)Lg, cnt);

    k_lred<<<dim3(NROWS / 128), 256, 0, stream>>>(Lg, labels, out_b, out);
}

// Round 14
// 539.251 us; speedup vs baseline: 1.3550x; 1.3550x over previous
//
#include <hip/hip_runtime.h>
#include <math.h>

typedef __bf16 bf16;
typedef __attribute__((ext_vector_type(4))) __bf16 bf16x4;
typedef __attribute__((ext_vector_type(8))) __bf16 bf16x8;
typedef __attribute__((ext_vector_type(4))) float f32x4;

#define T_STEPS 128
#define B_SZ    256
#define V_SZ    256
#define N_SZ    1024
#define NROWS   (T_STEPS * B_SZ)   // 32768
#define RSTR    68                 // step reduction stride (floats)
#define LSTR    17                 // loss reduction stride (floats)
#define NGRP    16                 // row groups (16 batch rows each)
#define NCB     16                 // col blocks per group (64 cols each)
// per-producer flag: own 128B line.  flg[FIDX(g,t,c)]
#define FIDX(g,t,c) ((((g) * T_STEPS + (t)) * 16 + (c)) * 32)
#define FLG_INTS    (NGRP * T_STEPS * 16 * 32)   // 4 MB

__device__ __forceinline__ float fast_tanh(float x) {
    float e = __expf(2.0f * x);
    return 1.0f - 2.0f / (e + 1.0f);   // exact at +-inf, no NaN
}

__device__ __forceinline__ bf16x8 cvt_bf16x8(float4 a, float4 b) {
    bf16x8 r;
    r[0] = (bf16)a.x; r[1] = (bf16)a.y; r[2] = (bf16)a.z; r[3] = (bf16)a.w;
    r[4] = (bf16)b.x; r[5] = (bf16)b.y; r[6] = (bf16)b.z; r[7] = (bf16)b.w;
    return r;
}

// ---------------- fp32 (R x C) -> bf16 transpose (C x R) ----------------
__global__ void k_transpose_cvt(const float* __restrict__ src, bf16* __restrict__ dst,
                                int R, int C) {
    __shared__ float tile[32][33];
    int c0 = blockIdx.x * 32;
    int r0 = blockIdx.y * 32;
    int tx = threadIdx.x & 31;
    int ty = threadIdx.x >> 5;   // 0..7
#pragma unroll
    for (int i = 0; i < 32; i += 8)
        tile[ty + i][tx] = src[(size_t)(r0 + ty + i) * C + c0 + tx];
    __syncthreads();
#pragma unroll
    for (int i = 0; i < 32; i += 8)
        dst[(size_t)(c0 + ty + i) * R + r0 + tx] = (bf16)tile[tx][ty + i];
}

// ---------------- persistent recurrence + fused Xproj + fused loss GEMM ------------
// v4 (on R11's proven base): per-PRODUCER flag sync. Wave w's A K-slice
// [w*128,+128) is produced by col-blocks 2w, 2w+1 only -> each wave polls just
// those two flags (plain relaxed stores on private 128B lines, no RMW; 16
// pollers/line spread over 16 lines). Early waves overlap A-load+MFMA with late
// producers. fp32 inputs read directly (k_convert fused). Logits row-major.
__global__ __launch_bounds__(512, 2) void k_rnn(
    const float* __restrict__ Xf,   // 32768 x 256 fp32 inputs (t-major)
    const bf16* __restrict__ Wxt,   // 1024 x 256  = Wx^T
    const bf16* __restrict__ Wht,   // 1024 x 1024 = Wh^T
    const bf16* __restrict__ Wot,   // 256 x 1024  = Wo^T
    const float* __restrict__ bias,
    bf16* __restrict__ XH,          // 32768 x 1024 H states
    unsigned int* __restrict__ Lgu, // bf16-pair logits, ROW-major [row][128 dwords]
    int* __restrict__ flg)          // per-producer flags, zeroed
{
    __shared__ float red[8 * 16 * RSTR];   // 34.8 KB step K-reduce
    __shared__ float lred[8 * 16 * LSTR];  // 8.7 KB  loss K-reduce
    const int tid  = threadIdx.x;
    const int lane = tid & 63;
    const int w    = tid >> 6;        // 0..7
    const int quad = lane >> 4;
    const int l15  = lane & 15;
    const int g  = blockIdx.x >> 4;   // row group
    const int c  = blockIdx.x & 15;   // col block / vocab slab
    const int m0 = g * 16;
    const int n0 = c * 64;
    const int k0 = w * 128;           // K-slice for Wh / Wot GEMMs
    const int v0 = w * 32;            // K-slice for Xproj GEMM (V=256 / 8)

    // hoisted B fragments (reloads come from hot L2 — never invalidated)
    const bf16* Bp = Wht + (size_t)(n0 + l15) * N_SZ + k0 + quad * 8;
    bf16x8 b[4][4];
#pragma unroll
    for (int nt = 0; nt < 4; ++nt)
#pragma unroll
        for (int kc = 0; kc < 4; ++kc)
            b[nt][kc] = *(const bf16x8*)&Bp[(size_t)(nt * 16) * N_SZ + kc * 32];
    bf16x8 bx[4];
#pragma unroll
    for (int nt = 0; nt < 4; ++nt)
        bx[nt] = *(const bf16x8*)&Wxt[(size_t)(n0 + nt * 16 + l15) * V_SZ + v0 + quad * 8];
    bf16x8 bo[4];
#pragma unroll
    for (int kc = 0; kc < 4; ++kc)
        bo[kc] = *(const bf16x8*)&Wot[(size_t)(c * 16 + l15) * N_SZ + k0 + kc * 32 + quad * 8];

    const int orow = tid >> 5;           // 0..15
    const int ocol = (tid & 31) * 2;     // 0..62
    const float bias0 = bias[n0 + ocol];
    const float bias1 = bias[n0 + ocol + 1];
    // loss epilogue mapping: 16 lanes/wave, rows w*2+(lane>>3), vp = lane&7
    const int lrow = w * 2 + (lane >> 3);
    const int lvp  = lane & 7;
    unsigned int* XHu = (unsigned int*)XH;
    const f32x4 zz = {0.f, 0.f, 0.f, 0.f};
    const size_t xin = (size_t)(m0 + l15) * V_SZ + v0 + quad * 8;

    // ---------------- t = 0: H_0 = tanh(Xproj_0 + bias) ----------------
    {
        float4 f0 = *(const float4*)&Xf[xin];
        float4 f1 = *(const float4*)&Xf[xin + 4];
        bf16x8 ax = cvt_bf16x8(f0, f1);
        f32x4 acc[4] = {zz, zz, zz, zz};
#pragma unroll
        for (int nt = 0; nt < 4; ++nt)
            acc[nt] = __builtin_amdgcn_mfma_f32_16x16x32_bf16(ax, bx[nt], acc[nt], 0, 0, 0);
#pragma unroll
        for (int nt = 0; nt < 4; ++nt)
#pragma unroll
            for (int r = 0; r < 4; ++r)
                red[(w * 16 + quad * 4 + r) * RSTR + nt * 16 + l15] = acc[nt][r];
        __syncthreads();
        float s0 = bias0, s1 = bias1;
#pragma unroll
        for (int w2 = 0; w2 < 8; ++w2) {
            float2 v = *(const float2*)&red[(w2 * 16 + orow) * RSTR + ocol];
            s0 += v.x; s1 += v.y;
        }
        bf16 r0 = (bf16)fast_tanh(s0);
        bf16 r1 = (bf16)fast_tanh(s1);
        unsigned int outw = (unsigned int)__builtin_bit_cast(unsigned short, r0)
                          | ((unsigned int)__builtin_bit_cast(unsigned short, r1) << 16);
        size_t oidx = (((size_t)m0 + orow) * N_SZ + n0 + ocol) >> 1;
        __hip_atomic_store(&XHu[oidx], outw, __ATOMIC_RELAXED, __HIP_MEMORY_SCOPE_AGENT);
        asm volatile("s_waitcnt vmcnt(0)" ::: "memory");
        __syncthreads();
        if (tid == 0)
            __hip_atomic_store(&flg[FIDX(g, 0, c)], 1,
                               __ATOMIC_RELAXED, __HIP_MEMORY_SCOPE_AGENT);
    }

    // ---------------- t = 1 .. 127 ----------------
    for (int t = 1; t < T_STEPS; ++t) {
        // Xproj input prefetch (fp32, in flight through the poll)
        float4 f0 = *(const float4*)&Xf[(size_t)t * B_SZ * V_SZ + xin];
        float4 f1 = *(const float4*)&Xf[(size_t)t * B_SZ * V_SZ + xin + 4];

        // per-wave poll of this wave's TWO producers for plane t-1
        if (lane == 0) {
            const int* fp0 = &flg[FIDX(g, t - 1, 2 * w)];
            while (__hip_atomic_load(fp0, __ATOMIC_RELAXED, __HIP_MEMORY_SCOPE_AGENT) == 0)
                __builtin_amdgcn_s_sleep(1);
            const int* fp1 = &flg[FIDX(g, t - 1, 2 * w + 1)];
            while (__hip_atomic_load(fp1, __ATOMIC_RELAXED, __HIP_MEMORY_SCOPE_AGENT) == 0)
                __builtin_amdgcn_s_sleep(1);
        }
        asm volatile("" ::: "memory");   // no A-load hoist above the poll

        // A fragments: 16 rows of H_{t-1}, this wave's K-slice (fresh from L3)
        const bf16* Ap = XH + ((size_t)(t - 1) * B_SZ + m0 + l15) * N_SZ + k0 + quad * 8;
        bf16x8 a[4];
#pragma unroll
        for (int kc = 0; kc < 4; ++kc)
            a[kc] = *(const bf16x8*)&Ap[kc * 32];

        bf16x8 ax = cvt_bf16x8(f0, f1);
        f32x4 acc[4] = {zz, zz, zz, zz};
#pragma unroll
        for (int nt = 0; nt < 4; ++nt)
            acc[nt] = __builtin_amdgcn_mfma_f32_16x16x32_bf16(ax, bx[nt], acc[nt], 0, 0, 0);
#pragma unroll
        for (int kc = 0; kc < 4; ++kc)
#pragma unroll
            for (int nt = 0; nt < 4; ++nt)
                acc[nt] = __builtin_amdgcn_mfma_f32_16x16x32_bf16(a[kc], b[nt][kc],
                                                                  acc[nt], 0, 0, 0);
        // loss MFMAs for plane t-1 (reuses a[])
        f32x4 lacc = zz;
#pragma unroll
        for (int kc = 0; kc < 4; ++kc)
            lacc = __builtin_amdgcn_mfma_f32_16x16x32_bf16(a[kc], bo[kc], lacc, 0, 0, 0);

#pragma unroll
        for (int nt = 0; nt < 4; ++nt)
#pragma unroll
            for (int r = 0; r < 4; ++r)
                red[(w * 16 + quad * 4 + r) * RSTR + nt * 16 + l15] = acc[nt][r];
#pragma unroll
        for (int r = 0; r < 4; ++r)
            lred[(w * 16 + quad * 4 + r) * LSTR + l15] = lacc[r];
        __syncthreads();

        // step epilogue: reduce, tanh, publish (write-through dword)
        float s0 = bias0, s1 = bias1;
#pragma unroll
        for (int w2 = 0; w2 < 8; ++w2) {
            float2 v = *(const float2*)&red[(w2 * 16 + orow) * RSTR + ocol];
            s0 += v.x; s1 += v.y;
        }
        bf16 r0 = (bf16)fast_tanh(s0);
        bf16 r1 = (bf16)fast_tanh(s1);
        unsigned int outw = (unsigned int)__builtin_bit_cast(unsigned short, r0)
                          | ((unsigned int)__builtin_bit_cast(unsigned short, r1) << 16);
        size_t oidx = (((size_t)t * B_SZ + m0 + orow) * N_SZ + n0 + ocol) >> 1;
        __hip_atomic_store(&XHu[oidx], outw, __ATOMIC_RELAXED, __HIP_MEMORY_SCOPE_AGENT);

        // loss epilogue: row-major bf16-pair logits
        if (lane < 16) {
            float sa = 0.f, sb = 0.f;
#pragma unroll
            for (int w2 = 0; w2 < 8; ++w2) {
                sa += lred[(w2 * 16 + lrow) * LSTR + lvp * 2];
                sb += lred[(w2 * 16 + lrow) * LSTR + lvp * 2 + 1];
            }
            bf16 pa = (bf16)sa, pb = (bf16)sb;
            unsigned int pw = (unsigned int)__builtin_bit_cast(unsigned short, pa)
                            | ((unsigned int)__builtin_bit_cast(unsigned short, pb) << 16);
            Lgu[((size_t)(t - 1) * B_SZ + m0 + lrow) * 128 + c * 8 + lvp] = pw;
        }

        // drain all stores, block barrier, publish own flag
        asm volatile("s_waitcnt vmcnt(0)" ::: "memory");
        __syncthreads();
        if (tid == 0)
            __hip_atomic_store(&flg[FIDX(g, t, c)], 1,
                               __ATOMIC_RELAXED, __HIP_MEMORY_SCOPE_AGENT);
    }

    // ---------------- tail: loss GEMM for plane 127 ----------------
    if (lane == 0) {
        const int* fp0 = &flg[FIDX(g, T_STEPS - 1, 2 * w)];
        while (__hip_atomic_load(fp0, __ATOMIC_RELAXED, __HIP_MEMORY_SCOPE_AGENT) == 0)
            __builtin_amdgcn_s_sleep(1);
        const int* fp1 = &flg[FIDX(g, T_STEPS - 1, 2 * w + 1)];
        while (__hip_atomic_load(fp1, __ATOMIC_RELAXED, __HIP_MEMORY_SCOPE_AGENT) == 0)
            __builtin_amdgcn_s_sleep(1);
    }
    asm volatile("" ::: "memory");
    {
        const bf16* Ap = XH + ((size_t)(T_STEPS - 1) * B_SZ + m0 + l15) * N_SZ + k0 + quad * 8;
        bf16x8 a[4];
#pragma unroll
        for (int kc = 0; kc < 4; ++kc)
            a[kc] = *(const bf16x8*)&Ap[kc * 32];
        f32x4 lacc = zz;
#pragma unroll
        for (int kc = 0; kc < 4; ++kc)
            lacc = __builtin_amdgcn_mfma_f32_16x16x32_bf16(a[kc], bo[kc], lacc, 0, 0, 0);
#pragma unroll
        for (int r = 0; r < 4; ++r)
            lred[(w * 16 + quad * 4 + r) * LSTR + l15] = lacc[r];
        __syncthreads();
        if (lane < 16) {
            float sa = 0.f, sb = 0.f;
#pragma unroll
            for (int w2 = 0; w2 < 8; ++w2) {
                sa += lred[(w2 * 16 + lrow) * LSTR + lvp * 2];
                sb += lred[(w2 * 16 + lrow) * LSTR + lvp * 2 + 1];
            }
            bf16 pa = (bf16)sa, pb = (bf16)sb;
            unsigned int pw = (unsigned int)__builtin_bit_cast(unsigned short, pa)
                            | ((unsigned int)__builtin_bit_cast(unsigned short, pb) << 16);
            Lgu[((size_t)(T_STEPS - 1) * B_SZ + m0 + lrow) * 128 + c * 8 + lvp] = pw;
        }
    }
}

// ---------------- final: log-softmax + weighted-label loss over bf16 logits --------
// Row-major logits -> fully coalesced reads. 256 blocks x 256 threads; wave = one
// row per iteration (lane covers vocab [lane*4,+4)), 32 rows/wave.
__global__ __launch_bounds__(256) void k_lred(
    const bf16* __restrict__ Lg,
    const float* __restrict__ labels,
    const float* __restrict__ ob,
    float* __restrict__ out)
{
    __shared__ float bt[4];
    const int tid  = threadIdx.x;
    const int lane = tid & 63;
    const int w    = tid >> 6;       // 0..3
    const float4 ob4 = *(const float4*)&ob[lane * 4];

    float wtot = 0.f;
    for (int i = 0; i < 32; ++i) {
        int row = blockIdx.x * 128 + w * 32 + i;
        bf16x4 lv = *(const bf16x4*)&Lg[(size_t)row * V_SZ + lane * 4];
        float l0 = (float)lv.x + ob4.x;
        float l1 = (float)lv.y + ob4.y;
        float l2 = (float)lv.z + ob4.z;
        float l3 = (float)lv.w + ob4.w;
        float mx = fmaxf(fmaxf(l0, l1), fmaxf(l2, l3));
#pragma unroll
        for (int sft = 1; sft < 64; sft <<= 1)
            mx = fmaxf(mx, __shfl_xor(mx, sft, 64));
        float sume = __expf(l0 - mx) + __expf(l1 - mx) + __expf(l2 - mx) + __expf(l3 - mx);
        const float4 lb = *(const float4*)&labels[(size_t)row * V_SZ + lane * 4];
        float labs = lb.x + lb.y + lb.z + lb.w;
        float labv = lb.x * l0 + lb.y * l1 + lb.z * l2 + lb.w * l3;
#pragma unroll
        for (int sft = 1; sft < 64; sft <<= 1) {
            sume += __shfl_xor(sume, sft, 64);
            labs += __shfl_xor(labs, sft, 64);
            labv += __shfl_xor(labv, sft, 64);
        }
        float lse = mx + __logf(sume);
        wtot += labs * lse - labv;
    }
    if (lane == 0) bt[w] = wtot;
    __syncthreads();
    if (tid == 0)
        atomicAdd(out, (bt[0] + bt[1] + bt[2] + bt[3]) * (1.0f / (float)NROWS));
}

extern "C" void kernel_launch(void* const* d_in, const int* in_sizes, int n_in,
                              void* d_out, int out_size, void* d_ws, size_t ws_size,
                              hipStream_t stream)
{
    const float* inputs  = (const float*)d_in[0];
    const float* labels  = (const float*)d_in[1];
    const float* weights = (const float*)d_in[2];
    const float* bias    = (const float*)d_in[3];
    const float* out_w   = (const float*)d_in[4];
    const float* out_b   = (const float*)d_in[5];
    float* out = (float*)d_out;

    char* ws = (char*)d_ws;
    bf16* XH  = (bf16*)ws;  ws += (size_t)NROWS * N_SZ * 2;   // 64 MB H states
    bf16* Lg  = (bf16*)ws;  ws += (size_t)NROWS * V_SZ * 2;   // 16 MB logits (row-major)
    bf16* Wxt = (bf16*)ws;  ws += (size_t)N_SZ * V_SZ * 2;    // 0.5 MB (Wx^T)
    bf16* Wht = (bf16*)ws;  ws += (size_t)N_SZ * N_SZ * 2;    // 2 MB   (Wh^T)
    bf16* Wot = (bf16*)ws;  ws += (size_t)V_SZ * N_SZ * 2;    // 0.5 MB (Wo^T)
    int*  flg = (int*)ws;   ws += (size_t)FLG_INTS * 4;       // 4 MB producer flags

    hipMemsetAsync(out, 0, sizeof(float), stream);
    hipMemsetAsync(flg, 0, (size_t)FLG_INTS * 4, stream);

    k_transpose_cvt<<<dim3(N_SZ / 32, V_SZ / 32), 256, 0, stream>>>(weights, Wxt, V_SZ, N_SZ);
    k_transpose_cvt<<<dim3(N_SZ / 32, N_SZ / 32), 256, 0, stream>>>(
        weights + (size_t)V_SZ * N_SZ, Wht, N_SZ, N_SZ);
    k_transpose_cvt<<<dim3(V_SZ / 32, N_SZ / 32), 256, 0, stream>>>(out_w, Wot, N_SZ, V_SZ);

    k_rnn<<<dim3(NGRP * NCB), 512, 0, stream>>>(inputs, Wxt, Wht, Wot, bias, XH,
                                                (unsigned int*)Lg, flg);

    k_lred<<<dim3(NROWS / 128), 256, 0, stream>>>(Lg, labels, out_b, out);
}

// Round 15
// 497.977 us; speedup vs baseline: 1.4673x; 1.0829x over previous
//
#include <hip/hip_runtime.h>
#include <math.h>

typedef __bf16 bf16;
typedef __attribute__((ext_vector_type(4))) __bf16 bf16x4;
typedef __attribute__((ext_vector_type(8))) __bf16 bf16x8;
typedef __attribute__((ext_vector_type(4))) float f32x4;

#define T_STEPS 128
#define B_SZ    256
#define V_SZ    256
#define N_SZ    1024
#define NROWS   (T_STEPS * B_SZ)   // 32768
#define RSTR    68                 // step reduction stride (floats)
#define LSTR    17                 // loss reduction stride (floats)
#define NGRP    16                 // row groups (16 batch rows each)
#define NCB     16                 // col blocks per group (64 cols each)

__device__ __forceinline__ float fast_tanh(float x) {
    float e = __expf(2.0f * x);
    return 1.0f - 2.0f / (e + 1.0f);   // exact at +-inf, no NaN
}

__device__ __forceinline__ bf16x8 cvt_bf16x8(float4 a, float4 b) {
    bf16x8 r;
    r[0] = (bf16)a.x; r[1] = (bf16)a.y; r[2] = (bf16)a.z; r[3] = (bf16)a.w;
    r[4] = (bf16)b.x; r[5] = (bf16)b.y; r[6] = (bf16)b.z; r[7] = (bf16)b.w;
    return r;
}

// ---------------- one-shot prep: all three fp32->bf16 transposes -------------------
// tile id space: [0,256) Wxt (V=256 rows -> 1024x256), [256,1280) Wht (1024x1024),
// [1280,1536) Wot (1024 rows -> 256x1024).
__global__ __launch_bounds__(256) void k_prep(
    const float* __restrict__ weights,   // (V+N) x N  = 1280 x 1024
    const float* __restrict__ out_w,     // N x V      = 1024 x 256
    bf16* __restrict__ Wxt,              // 1024 x 256
    bf16* __restrict__ Wht,              // 1024 x 1024
    bf16* __restrict__ Wot)              // 256 x 1024
{
    __shared__ float tile[32][33];
    int id = blockIdx.x;
    const float* src; bf16* dst; int R, C, tr, tc;
    if (id < 256) {            // Wx: rows 0..255 of weights -> Wxt
        src = weights; dst = Wxt; R = V_SZ; C = N_SZ;
        tr = (id & 7) * 32; tc = (id >> 3) * 32;          // 8 row-tiles x 32 col-tiles
    } else if (id < 1280) {    // Wh: rows 256..1279 of weights -> Wht
        id -= 256;
        src = weights + (size_t)V_SZ * N_SZ; dst = Wht; R = N_SZ; C = N_SZ;
        tr = (id & 31) * 32; tc = (id >> 5) * 32;
    } else {                   // Wo: out_w -> Wot
        id -= 1280;
        src = out_w; dst = Wot; R = N_SZ; C = V_SZ;
        tr = (id & 31) * 32; tc = (id >> 5) * 32;
    }
    int tx = threadIdx.x & 31;
    int ty = threadIdx.x >> 5;   // 0..7
#pragma unroll
    for (int i = 0; i < 32; i += 8)
        tile[ty + i][tx] = src[(size_t)(tr + ty + i) * C + tc + tx];
    __syncthreads();
#pragma unroll
    for (int i = 0; i < 32; i += 8)
        dst[(size_t)(tc + ty + i) * R + tr + tx] = (bf16)tile[tx][ty + i];
}

// ---------------- persistent recurrence + fused Xproj + fused loss GEMM ------------
// R11 structure (proven best sync: per-block counter, 16 arrivals, tid0 poll+arrive,
// 3 barriers/step) + fp32 inputs read directly (k_convert fused away).
// Slab logit layout: each wave's logit store is one contiguous cache line.
// No acquire fences anywhere => Wht/Wxt/Wot stay L2-hot for the whole kernel.
__global__ __launch_bounds__(512, 2) void k_rnn(
    const float* __restrict__ Xf,   // 32768 x 256 fp32 inputs (t-major)
    const bf16* __restrict__ Wxt,   // 1024 x 256  = Wx^T
    const bf16* __restrict__ Wht,   // 1024 x 1024 = Wh^T
    const bf16* __restrict__ Wot,   // 256 x 1024  = Wo^T
    const float* __restrict__ bias,
    bf16* __restrict__ XH,          // 32768 x 1024 H states
    unsigned int* __restrict__ Lgu, // bf16-pair logits, slab layout [p][c][256][8]
    int* __restrict__ cnt)          // [NGRP * T_STEPS], zeroed
{
    __shared__ float red[8 * 16 * RSTR];   // 34.8 KB step K-reduce
    __shared__ float lred[8 * 16 * LSTR];  // 8.7 KB  loss K-reduce
    const int tid  = threadIdx.x;
    const int lane = tid & 63;
    const int w    = tid >> 6;        // 0..7
    const int quad = lane >> 4;
    const int l15  = lane & 15;
    const int g  = blockIdx.x >> 4;   // row group
    const int c  = blockIdx.x & 15;   // col block / vocab slab
    const int m0 = g * 16;
    const int n0 = c * 64;
    const int k0 = w * 128;           // K-slice for Wh / Wot GEMMs
    const int v0 = w * 32;            // K-slice for Xproj GEMM (V=256 / 8)
    int* gcnt = cnt + g * T_STEPS;

    // hoisted B fragments (reloads come from hot L2 — never invalidated)
    const bf16* Bp = Wht + (size_t)(n0 + l15) * N_SZ + k0 + quad * 8;
    bf16x8 b[4][4];
#pragma unroll
    for (int nt = 0; nt < 4; ++nt)
#pragma unroll
        for (int kc = 0; kc < 4; ++kc)
            b[nt][kc] = *(const bf16x8*)&Bp[(size_t)(nt * 16) * N_SZ + kc * 32];
    bf16x8 bx[4];
#pragma unroll
    for (int nt = 0; nt < 4; ++nt)
        bx[nt] = *(const bf16x8*)&Wxt[(size_t)(n0 + nt * 16 + l15) * V_SZ + v0 + quad * 8];
    bf16x8 bo[4];
#pragma unroll
    for (int kc = 0; kc < 4; ++kc)
        bo[kc] = *(const bf16x8*)&Wot[(size_t)(c * 16 + l15) * N_SZ + k0 + kc * 32 + quad * 8];

    const int orow = tid >> 5;           // 0..15
    const int ocol = (tid & 31) * 2;     // 0..62
    const float bias0 = bias[n0 + ocol];
    const float bias1 = bias[n0 + ocol + 1];
    // loss epilogue mapping: 16 lanes/wave, rows w*2+(lane>>3), vp = lane&7
    const int lrow = w * 2 + (lane >> 3);
    const int lvp  = lane & 7;
    unsigned int* XHu = (unsigned int*)XH;
    const f32x4 zz = {0.f, 0.f, 0.f, 0.f};
    const size_t xin = (size_t)(m0 + l15) * V_SZ + v0 + quad * 8;

    // ---------------- t = 0: H_0 = tanh(Xproj_0 + bias) ----------------
    {
        float4 f0 = *(const float4*)&Xf[xin];
        float4 f1 = *(const float4*)&Xf[xin + 4];
        bf16x8 ax = cvt_bf16x8(f0, f1);
        f32x4 acc[4] = {zz, zz, zz, zz};
#pragma unroll
        for (int nt = 0; nt < 4; ++nt)
            acc[nt] = __builtin_amdgcn_mfma_f32_16x16x32_bf16(ax, bx[nt], acc[nt], 0, 0, 0);
#pragma unroll
        for (int nt = 0; nt < 4; ++nt)
#pragma unroll
            for (int r = 0; r < 4; ++r)
                red[(w * 16 + quad * 4 + r) * RSTR + nt * 16 + l15] = acc[nt][r];
        __syncthreads();
        float s0 = bias0, s1 = bias1;
#pragma unroll
        for (int w2 = 0; w2 < 8; ++w2) {
            float2 v = *(const float2*)&red[(w2 * 16 + orow) * RSTR + ocol];
            s0 += v.x; s1 += v.y;
        }
        bf16 r0 = (bf16)fast_tanh(s0);
        bf16 r1 = (bf16)fast_tanh(s1);
        unsigned int outw = (unsigned int)__builtin_bit_cast(unsigned short, r0)
                          | ((unsigned int)__builtin_bit_cast(unsigned short, r1) << 16);
        size_t oidx = (((size_t)m0 + orow) * N_SZ + n0 + ocol) >> 1;
        __hip_atomic_store(&XHu[oidx], outw, __ATOMIC_RELAXED, __HIP_MEMORY_SCOPE_AGENT);
        asm volatile("s_waitcnt vmcnt(0)" ::: "memory");
        __syncthreads();
        if (tid == 0)
            __hip_atomic_fetch_add(&gcnt[0], 1, __ATOMIC_RELAXED, __HIP_MEMORY_SCOPE_AGENT);
    }

    // ---------------- t = 1 .. 127 ----------------
    for (int t = 1; t < T_STEPS; ++t) {
        // Xproj input prefetch (fp32, in flight through the poll)
        float4 f0 = *(const float4*)&Xf[(size_t)t * B_SZ * V_SZ + xin];
        float4 f1 = *(const float4*)&Xf[(size_t)t * B_SZ * V_SZ + xin + 4];

        // block-level poll: ONE poller + ONE arrive atomic per block per step
        if (tid == 0) {
            while (__hip_atomic_load(&gcnt[t - 1], __ATOMIC_RELAXED,
                                     __HIP_MEMORY_SCOPE_AGENT) < NCB)
                __builtin_amdgcn_s_sleep(1);
        }
        __syncthreads();

        // A fragments: 16 rows of H_{t-1} (first regular-load touch => fresh from L3)
        const bf16* Ap = XH + ((size_t)(t - 1) * B_SZ + m0 + l15) * N_SZ + k0 + quad * 8;
        bf16x8 a[4];
#pragma unroll
        for (int kc = 0; kc < 4; ++kc)
            a[kc] = *(const bf16x8*)&Ap[kc * 32];

        bf16x8 ax = cvt_bf16x8(f0, f1);
        f32x4 acc[4] = {zz, zz, zz, zz};
#pragma unroll
        for (int nt = 0; nt < 4; ++nt)
            acc[nt] = __builtin_amdgcn_mfma_f32_16x16x32_bf16(ax, bx[nt], acc[nt], 0, 0, 0);
#pragma unroll
        for (int kc = 0; kc < 4; ++kc)
#pragma unroll
            for (int nt = 0; nt < 4; ++nt)
                acc[nt] = __builtin_amdgcn_mfma_f32_16x16x32_bf16(a[kc], b[nt][kc],
                                                                  acc[nt], 0, 0, 0);
        // loss MFMAs for plane t-1 (reuses a[])
        f32x4 lacc = zz;
#pragma unroll
        for (int kc = 0; kc < 4; ++kc)
            lacc = __builtin_amdgcn_mfma_f32_16x16x32_bf16(a[kc], bo[kc], lacc, 0, 0, 0);

        // both K-reduce writes in ONE window
#pragma unroll
        for (int nt = 0; nt < 4; ++nt)
#pragma unroll
            for (int r = 0; r < 4; ++r)
                red[(w * 16 + quad * 4 + r) * RSTR + nt * 16 + l15] = acc[nt][r];
#pragma unroll
        for (int r = 0; r < 4; ++r)
            lred[(w * 16 + quad * 4 + r) * LSTR + l15] = lacc[r];
        __syncthreads();

        // step epilogue: reduce, tanh, publish (write-through dword)
        float s0 = bias0, s1 = bias1;
#pragma unroll
        for (int w2 = 0; w2 < 8; ++w2) {
            float2 v = *(const float2*)&red[(w2 * 16 + orow) * RSTR + ocol];
            s0 += v.x; s1 += v.y;
        }
        bf16 r0 = (bf16)fast_tanh(s0);
        bf16 r1 = (bf16)fast_tanh(s1);
        unsigned int outw = (unsigned int)__builtin_bit_cast(unsigned short, r0)
                          | ((unsigned int)__builtin_bit_cast(unsigned short, r1) << 16);
        size_t oidx = (((size_t)t * B_SZ + m0 + orow) * N_SZ + n0 + ocol) >> 1;
        __hip_atomic_store(&XHu[oidx], outw, __ATOMIC_RELAXED, __HIP_MEMORY_SCOPE_AGENT);

        // loss epilogue (16 lanes per wave, own rows; slab layout = 1 line/wave)
        if (lane < 16) {
            float sa = 0.f, sb = 0.f;
#pragma unroll
            for (int w2 = 0; w2 < 8; ++w2) {
                sa += lred[(w2 * 16 + lrow) * LSTR + lvp * 2];
                sb += lred[(w2 * 16 + lrow) * LSTR + lvp * 2 + 1];
            }
            bf16 pa = (bf16)sa, pb = (bf16)sb;
            unsigned int pw = (unsigned int)__builtin_bit_cast(unsigned short, pa)
                            | ((unsigned int)__builtin_bit_cast(unsigned short, pb) << 16);
            Lgu[(((size_t)(t - 1) * 16 + c) * B_SZ + m0 + lrow) * 8 + lvp] = pw;
        }

        // drain stores (per-wave), barrier (all drained + LDS reads done), arrive
        asm volatile("s_waitcnt vmcnt(0)" ::: "memory");
        __syncthreads();
        if (tid == 0)
            __hip_atomic_fetch_add(&gcnt[t], 1, __ATOMIC_RELAXED, __HIP_MEMORY_SCOPE_AGENT);
    }

    // ---------------- tail: loss GEMM for plane 127 ----------------
    if (tid == 0) {
        while (__hip_atomic_load(&gcnt[T_STEPS - 1], __ATOMIC_RELAXED,
                                 __HIP_MEMORY_SCOPE_AGENT) < NCB)
            __builtin_amdgcn_s_sleep(1);
    }
    __syncthreads();
    {
        const bf16* Ap = XH + ((size_t)(T_STEPS - 1) * B_SZ + m0 + l15) * N_SZ + k0 + quad * 8;
        bf16x8 a[4];
#pragma unroll
        for (int kc = 0; kc < 4; ++kc)
            a[kc] = *(const bf16x8*)&Ap[kc * 32];
        f32x4 lacc = zz;
#pragma unroll
        for (int kc = 0; kc < 4; ++kc)
            lacc = __builtin_amdgcn_mfma_f32_16x16x32_bf16(a[kc], bo[kc], lacc, 0, 0, 0);
#pragma unroll
        for (int r = 0; r < 4; ++r)
            lred[(w * 16 + quad * 4 + r) * LSTR + l15] = lacc[r];
        __syncthreads();
        if (lane < 16) {
            float sa = 0.f, sb = 0.f;
#pragma unroll
            for (int w2 = 0; w2 < 8; ++w2) {
                sa += lred[(w2 * 16 + lrow) * LSTR + lvp * 2];
                sb += lred[(w2 * 16 + lrow) * LSTR + lvp * 2 + 1];
            }
            bf16 pa = (bf16)sa, pb = (bf16)sb;
            unsigned int pw = (unsigned int)__builtin_bit_cast(unsigned short, pa)
                            | ((unsigned int)__builtin_bit_cast(unsigned short, pb) << 16);
            Lgu[(((size_t)(T_STEPS - 1) * 16 + c) * B_SZ + m0 + lrow) * 8 + lvp] = pw;
        }
    }
}

// ---------------- final: log-softmax + weighted-label loss over bf16 logits --------
// 256 blocks x 256 threads (4 waves); block handles 128 rows, wave 32 rows.
// Logits layout: [plane][cslab 16][row-in-plane 256][16 vocab] bf16.
__global__ __launch_bounds__(256) void k_lred(
    const bf16* __restrict__ Lg,
    const float* __restrict__ labels,
    const float* __restrict__ ob,
    float* __restrict__ out)
{
    __shared__ float bt[4];
    const int tid  = threadIdx.x;
    const int lane = tid & 63;
    const int w    = tid >> 6;       // 0..3
    const int cs   = lane >> 2;      // vocab slab 0..15
    const int vi   = (lane & 3) * 4; // offset in slab
    const float4 ob4 = *(const float4*)&ob[cs * 16 + vi];

    float wtot = 0.f;
    for (int i = 0; i < 32; ++i) {
        int row  = blockIdx.x * 128 + w * 32 + i;
        int p    = row >> 8;
        int brow = row & 255;
        bf16x4 lv = *(const bf16x4*)&Lg[(((size_t)p * 16 + cs) * B_SZ + brow) * 16 + vi];
        float l0 = (float)lv.x + ob4.x;
        float l1 = (float)lv.y + ob4.y;
        float l2 = (float)lv.z + ob4.z;
        float l3 = (float)lv.w + ob4.w;
        float mx = fmaxf(fmaxf(l0, l1), fmaxf(l2, l3));
#pragma unroll
        for (int sft = 1; sft < 64; sft <<= 1)
            mx = fmaxf(mx, __shfl_xor(mx, sft, 64));
        float sume = __expf(l0 - mx) + __expf(l1 - mx) + __expf(l2 - mx) + __expf(l3 - mx);
        const float4 lb = *(const float4*)&labels[(size_t)row * V_SZ + cs * 16 + vi];
        float labs = lb.x + lb.y + lb.z + lb.w;
        float labv = lb.x * l0 + lb.y * l1 + lb.z * l2 + lb.w * l3;
#pragma unroll
        for (int sft = 1; sft < 64; sft <<= 1) {
            sume += __shfl_xor(sume, sft, 64);
            labs += __shfl_xor(labs, sft, 64);
            labv += __shfl_xor(labv, sft, 64);
        }
        float lse = mx + __logf(sume);
        wtot += labs * lse - labv;
    }
    if (lane == 0) bt[w] = wtot;
    __syncthreads();
    if (tid == 0)
        atomicAdd(out, (bt[0] + bt[1] + bt[2] + bt[3]) * (1.0f / (float)NROWS));
}

extern "C" void kernel_launch(void* const* d_in, const int* in_sizes, int n_in,
                              void* d_out, int out_size, void* d_ws, size_t ws_size,
                              hipStream_t stream)
{
    const float* inputs  = (const float*)d_in[0];
    const float* labels  = (const float*)d_in[1];
    const float* weights = (const float*)d_in[2];
    const float* bias    = (const float*)d_in[3];
    const float* out_w   = (const float*)d_in[4];
    const float* out_b   = (const float*)d_in[5];
    float* out = (float*)d_out;

    char* ws = (char*)d_ws;
    bf16* XH  = (bf16*)ws;  ws += (size_t)NROWS * N_SZ * 2;   // 64 MB H states
    bf16* Lg  = (bf16*)ws;  ws += (size_t)NROWS * V_SZ * 2;   // 16 MB logits (slab)
    bf16* Wxt = (bf16*)ws;  ws += (size_t)N_SZ * V_SZ * 2;    // 0.5 MB (Wx^T)
    bf16* Wht = (bf16*)ws;  ws += (size_t)N_SZ * N_SZ * 2;    // 2 MB   (Wh^T)
    bf16* Wot = (bf16*)ws;  ws += (size_t)V_SZ * N_SZ * 2;    // 0.5 MB (Wo^T)
    int*  cnt = (int*)ws;   ws += (size_t)NGRP * T_STEPS * 4; // 8 KB sync counters

    hipMemsetAsync(out, 0, sizeof(float), stream);
    hipMemsetAsync(cnt, 0, (size_t)NGRP * T_STEPS * 4, stream);

    k_prep<<<dim3(1536), 256, 0, stream>>>(weights, out_w, Wxt, Wht, Wot);

    k_rnn<<<dim3(NGRP * NCB), 512, 0, stream>>>(inputs, Wxt, Wht, Wot, bias, XH,
                                                (unsigned int*)Lg, cnt);

    k_lred<<<dim3(NROWS / 128), 256, 0, stream>>>(Lg, labels, out_b, out);
}